// Round 6
// baseline (167.747 us; speedup 1.0000x reference)
//
#include <hip/hip_runtime.h>

// MechanisticNRTLLoss — B=1e6 samples, scalar fp32 loss.
// R15 = R14 resubmitted (round-5 bench was an infra failure; audit found no
// hang/OOB/alignment/graph-capture hazard in the kernel).
// Block-cooperative LDS staging, 1 sample/thread.
//  - Each full block stages its 40KB input tile into LDS with <=12 coalesced
//    dwordx4 loads + ds_write_b128 per thread, one barrier, then computes
//    from LDS with immediate-offset reads. Replaces 35 narrow per-thread
//    VMEM ops + address math (R9) without the per-thread register doubling
//    that sank R11 (spills) — LDS holds the data, not VGPRs.
//  - Compute phase identical math to R11/R13 (strength-reduced ln_gamma3).
//  - LDS 40960B/block -> 4 blocks/CU cap (16 waves/CU >= current 12.7).
//  - Tail block (B%256 != 0) takes a direct-load path (block-uniform branch).

constexpr float ALPHA    = 0.3f;
constexpr float R_GAS    = 8.314462618f;
constexpr float EPS      = 1e-12f;
constexpr float TAU_CLIP = 10.0f;
constexpr float LN_CLIP  = 20.0f;
constexpr float EPS_FD   = 1e-4f;

constexpr float LOG2E = 1.44269504088896340736f;
constexpr float LN2   = 0.69314718055994530942f;

typedef float v4f __attribute__((ext_vector_type(4)));

__device__ __forceinline__ float clipf(float v, float lo, float hi) {
    return fminf(fmaxf(v, lo), hi);
}
__device__ __forceinline__ float fast_rcp(float x) { return __builtin_amdgcn_rcpf(x); }
__device__ __forceinline__ v4f nt_load4(const float* p) {
    return __builtin_nontemporal_load((const v4f*)p);
}
__device__ __forceinline__ float nt_load(const float* p) {
    return __builtin_nontemporal_load(p);
}

struct Mats {
    float tau[3][3];
    float G[3][3];
    float tG[3][3];
};

// per-sample staged inputs (40 floats)
struct SIn {
    float p[6];
    float t[6];
    float T;
    float g[9];
    float dv[2][3];
    float nv[4][3];
};

// ln_gamma for a 3-component system.
//   term2_ij = c_j*(tG_ij - G_ij*ratio_j),  c_j = x_j*invd_j   (2 FMA per term)
__device__ __forceinline__ void ln_gamma3(const float x[3], const Mats& M, float lg[3]) {
    float ratio[3], c[3];
#pragma unroll
    for (int i = 0; i < 3; ++i) {
        float d = x[0] * M.G[0][i] + x[1] * M.G[1][i] + x[2] * M.G[2][i];
        d = fmaxf(d, EPS);
        float A = x[0] * M.tG[0][i] + x[1] * M.tG[1][i] + x[2] * M.tG[2][i];
        float inv = fast_rcp(d);
        ratio[i] = A * inv;
        c[i] = x[i] * inv;
    }
#pragma unroll
    for (int i = 0; i < 3; ++i) {
        float s = ratio[i];
#pragma unroll
        for (int j = 0; j < 3; ++j) {
            s += c[j] * (M.tG[i][j] - M.G[i][j] * ratio[j]);
        }
        lg[i] = clipf(s, -LN_CLIP, LN_CLIP);
    }
}

__device__ __forceinline__ void renorm3(float x[3]) {
    x[0] = fmaxf(x[0], 0.0f);
    x[1] = fmaxf(x[1], 0.0f);
    x[2] = fmaxf(x[2], 0.0f);
    float inv = fast_rcp(fmaxf(x[0] + x[1] + x[2], EPS));
    x[0] *= inv; x[1] *= inv; x[2] *= inv;
}

// full per-sample loss term: sup/6 + phy/3 + 0.05*gd + 0.025*tpd
__device__ __forceinline__ float sample_contrib(const SIn& in) {
    float sup;
    {
        float d0 = in.p[0] - in.t[0], d1 = in.p[1] - in.t[1];
        float d2 = in.p[2] - in.t[2], d3 = in.p[3] - in.t[3];
        float d4 = in.p[4] - in.t[4], d5 = in.p[5] - in.t[5];
        sup = d0 * d0 + d1 * d1 + d2 * d2 + d3 * d3 + d4 * d4 + d5 * d5;
    }

    float xE[3] = {in.p[0], in.p[1], in.p[2]};
    float xR[3] = {in.p[3], in.p[4], in.p[5]};
    renorm3(xE);
    renorm3(xR);

    const float Tc = fmaxf(in.T, 1.0f);
    const float invRT = fast_rcp(R_GAS * Tc);
    Mats M;
#pragma unroll
    for (int a = 0; a < 3; ++a) {
#pragma unroll
        for (int b = 0; b < 3; ++b) {
            float ta = clipf(in.g[a * 3 + b] * invRT, -TAU_CLIP, TAU_CLIP);
            float Gv = __builtin_amdgcn_exp2f((-ALPHA * LOG2E) * ta);
            M.tau[a][b] = ta;
            M.G[a][b]   = Gv;
            M.tG[a][b]  = ta * Gv;
        }
    }

    float lgE[3], lgR[3];
    ln_gamma3(xE, M, lgE);
    ln_gamma3(xR, M, lgR);

    float logxE[3];
    float phy = 0.0f;
#pragma unroll
    for (int k = 0; k < 3; ++k) {
        logxE[k] = LN2 * __builtin_amdgcn_logf(fmaxf(xE[k], EPS));
        float logxR = LN2 * __builtin_amdgcn_logf(fmaxf(xR[k], EPS));
        float r = logxE[k] + lgE[k] - logxR - lgR[k];
        phy += r * r;
    }

    float gdsum = 0.0f;
#pragma unroll
    for (int d = 0; d < 2; ++d) {
        float xp[3], xm[3];
#pragma unroll
        for (int k = 0; k < 3; ++k) {
            xp[k] = xE[k] + EPS_FD * in.dv[d][k];
            xm[k] = xE[k] - EPS_FD * in.dv[d][k];
        }
        renorm3(xp);
        renorm3(xm);
        float lgp[3], lgm[3];
        ln_gamma3(xp, M, lgp);
        ln_gamma3(xm, M, lgm);
        float gd = 0.0f;
#pragma unroll
        for (int k = 0; k < 3; ++k) gd += xE[k] * (lgp[k] - lgm[k]);
        gd *= 0.5f / EPS_FD;
        gdsum += gd * gd;
    }

    float base[3];
#pragma unroll
    for (int k = 0; k < 3; ++k) base[k] = logxE[k] + lgE[k];

    float tpdsum = 0.0f;
#pragma unroll
    for (int tr = 0; tr < 4; ++tr) {
        float w[3];
#pragma unroll
        for (int k = 0; k < 3; ++k) w[k] = xE[k] + in.nv[tr][k];
        renorm3(w);
        float lgw[3];
        ln_gamma3(w, M, lgw);
        float tpd = 0.0f;
#pragma unroll
        for (int k = 0; k < 3; ++k) {
            float logw = LN2 * __builtin_amdgcn_logf(fmaxf(w[k], EPS));
            tpd += w[k] * (logw + lgw[k] - base[k]);
        }
        tpdsum += fmaxf(-tpd, 0.0f);  // MARGIN = 0
    }

    return sup * (1.0f / 6.0f)
         + phy * (1.0f / 3.0f)
         + 0.05f * gdsum
         + 0.025f * tpdsum;
}

__global__ __launch_bounds__(256) void nrtl_loss_kernel(
    const float* __restrict__ pred,   // (B,6)
    const float* __restrict__ target, // (B,6)
    const float* __restrict__ Tarr,   // (B,)
    const float* __restrict__ g,      // (B,3,3)
    const float* __restrict__ dirs,   // (2,B,3)
    const float* __restrict__ noise,  // (4,B,3)
    float* __restrict__ partials, int B)
{
    // LDS tile layout (bytes):
    //   pred   [    0,  6144)   24B/sample
    //   target [ 6144, 12288)
    //   T      [12288, 13312)    4B/sample
    //   g      [13312, 22528)   36B/sample
    //   dirs   [22528, 28672)   slice d at +3072*d, 12B/sample
    //   noise  [28672, 40960)   trial tr at +3072*tr, 12B/sample
    constexpr int OFF_T  = 6144;
    constexpr int OFF_TP = 12288;
    constexpr int OFF_G  = 13312;
    constexpr int OFF_D  = 22528;
    constexpr int OFF_N  = 28672;

    __shared__ __align__(16) char smem[40960];
    const int tid = threadIdx.x;
    const int s0  = blockIdx.x << 8;   // 256 samples per block

    float contrib = 0.0f;

    if (s0 + 256 <= B) {
        // ============ cooperative staged loads (16B chunks) ============
        // chunk c of a region lives at region_off + 16*c; thread t owns
        // chunks {t, t+256, t+512} (masked by region chunk count).
        const float* gp = pred   + (size_t)s0 * 6;   // 384 chunks
        const float* gt = target + (size_t)s0 * 6;   // 384 chunks
        const float* gT = Tarr   + s0;               //  64 chunks
        const float* gG = g      + (size_t)s0 * 9;   // 576 chunks

        v4f vp0 = nt_load4(gp + tid * 4);
        v4f vt0 = nt_load4(gt + tid * 4);
        v4f vg0 = nt_load4(gG + tid * 4);
        v4f vg1 = nt_load4(gG + (256 + tid) * 4);
        v4f vp1, vt1, vT4, vg2;
        if (tid < 128) {
            vp1 = nt_load4(gp + (256 + tid) * 4);
            vt1 = nt_load4(gt + (256 + tid) * 4);
        }
        if (tid < 64) {
            vT4 = nt_load4(gT + tid * 4);
            vg2 = nt_load4(gG + (512 + tid) * 4);
        }
        v4f vd0, vd1, vn0, vn1, vn2, vn3;           // 192 chunks each
        if (tid < 192) {
            vd0 = nt_load4(dirs  + ((size_t)0 * B + s0) * 3 + tid * 4);
            vd1 = nt_load4(dirs  + ((size_t)1 * B + s0) * 3 + tid * 4);
            vn0 = nt_load4(noise + ((size_t)0 * B + s0) * 3 + tid * 4);
            vn1 = nt_load4(noise + ((size_t)1 * B + s0) * 3 + tid * 4);
            vn2 = nt_load4(noise + ((size_t)2 * B + s0) * 3 + tid * 4);
            vn3 = nt_load4(noise + ((size_t)3 * B + s0) * 3 + tid * 4);
        }

        char* sw = smem + tid * 16;
        *(v4f*)(sw)                = vp0;
        *(v4f*)(sw + OFF_T)        = vt0;
        *(v4f*)(sw + OFF_G)        = vg0;
        *(v4f*)(sw + OFF_G + 4096) = vg1;
        if (tid < 128) {
            *(v4f*)(sw + 4096)         = vp1;
            *(v4f*)(sw + OFF_T + 4096) = vt1;
        }
        if (tid < 64) {
            *(v4f*)(sw + OFF_TP)       = vT4;
            *(v4f*)(sw + OFF_G + 8192) = vg2;
        }
        if (tid < 192) {
            *(v4f*)(sw + OFF_D)        = vd0;
            *(v4f*)(sw + OFF_D + 3072) = vd1;
            *(v4f*)(sw + OFF_N)        = vn0;
            *(v4f*)(sw + OFF_N + 3072) = vn1;
            *(v4f*)(sw + OFF_N + 6144) = vn2;
            *(v4f*)(sw + OFF_N + 9216) = vn3;
        }
        __syncthreads();

        // ============ per-sample gather from LDS ============
        SIn in;
        {
            const float* LP = (const float*)(smem)          + tid * 6;
            const float* LT = (const float*)(smem + OFF_T)  + tid * 6;
#pragma unroll
            for (int k = 0; k < 6; ++k) { in.p[k] = LP[k]; in.t[k] = LT[k]; }
            in.T = ((const float*)(smem + OFF_TP))[tid];
            const float* LG = (const float*)(smem + OFF_G)  + tid * 9;
#pragma unroll
            for (int k = 0; k < 9; ++k) in.g[k] = LG[k];
#pragma unroll
            for (int d = 0; d < 2; ++d) {
                const float* LD = (const float*)(smem + OFF_D + 3072 * d) + tid * 3;
#pragma unroll
                for (int k = 0; k < 3; ++k) in.dv[d][k] = LD[k];
            }
#pragma unroll
            for (int tr = 0; tr < 4; ++tr) {
                const float* LN = (const float*)(smem + OFF_N + 3072 * tr) + tid * 3;
#pragma unroll
                for (int k = 0; k < 3; ++k) in.nv[tr][k] = LN[k];
            }
        }
        contrib = sample_contrib(in) * (1.0f / (float)B);
    } else {
        // ---- tail block: direct loads, guarded ----
        const int i = s0 + tid;
        if (i < B) {
            SIn in;
            const float* prow = pred   + (size_t)i * 6;
            const float* trow = target + (size_t)i * 6;
            const float* grow = g      + (size_t)i * 9;
#pragma unroll
            for (int k = 0; k < 6; ++k) { in.p[k] = nt_load(prow + k); in.t[k] = nt_load(trow + k); }
            in.T = nt_load(Tarr + i);
#pragma unroll
            for (int k = 0; k < 9; ++k) in.g[k] = nt_load(grow + k);
#pragma unroll
            for (int d = 0; d < 2; ++d) {
                const float* drow = dirs + ((size_t)d * B + i) * 3;
#pragma unroll
                for (int k = 0; k < 3; ++k) in.dv[d][k] = nt_load(drow + k);
            }
#pragma unroll
            for (int tr = 0; tr < 4; ++tr) {
                const float* nrow = noise + ((size_t)tr * B + i) * 3;
#pragma unroll
                for (int k = 0; k < 3; ++k) in.nv[tr][k] = nt_load(nrow + k);
            }
            contrib = sample_contrib(in) * (1.0f / (float)B);
        }
    }

    // ---- block reduction: wave shuffle then LDS across 4 waves ----
#pragma unroll
    for (int off = 32; off > 0; off >>= 1)
        contrib += __shfl_down(contrib, off, 64);

    __shared__ float ssum[4];
    const int lane = threadIdx.x & 63;
    const int wid  = threadIdx.x >> 6;
    if (lane == 0) ssum[wid] = contrib;
    __syncthreads();
    if (threadIdx.x == 0) {
        partials[blockIdx.x] = ssum[0] + ssum[1] + ssum[2] + ssum[3];
    }
}

__global__ __launch_bounds__(256) void reduce_kernel(
    const float* __restrict__ partials, int n, float* __restrict__ out)
{
    double sacc = 0.0;
    for (int j = threadIdx.x; j < n; j += 256) sacc += (double)partials[j];
#pragma unroll
    for (int off = 32; off > 0; off >>= 1)
        sacc += __shfl_down(sacc, off, 64);
    __shared__ double ds[4];
    const int lane = threadIdx.x & 63;
    const int wid  = threadIdx.x >> 6;
    if (lane == 0) ds[wid] = sacc;
    __syncthreads();
    if (threadIdx.x == 0) out[0] = (float)(ds[0] + ds[1] + ds[2] + ds[3]);
}

extern "C" void kernel_launch(void* const* d_in, const int* in_sizes, int n_in,
                              void* d_out, int out_size, void* d_ws, size_t ws_size,
                              hipStream_t stream) {
    const float* pred   = (const float*)d_in[0];
    const float* target = (const float*)d_in[1];
    const float* Tarr   = (const float*)d_in[2];
    const float* g      = (const float*)d_in[3];
    const float* dirs   = (const float*)d_in[4];
    const float* noise  = (const float*)d_in[5];
    const int B = in_sizes[2];  // T is (B,)

    float* partials = (float*)d_ws;
    float* out      = (float*)d_out;

    const int block = 256;
    const int grid  = (B + block - 1) / block;
    nrtl_loss_kernel<<<grid, block, 0, stream>>>(pred, target, Tarr, g, dirs, noise, partials, B);
    reduce_kernel<<<1, block, 0, stream>>>(partials, grid, out);
}